// Round 1
// 563.601 us; speedup vs baseline: 1.0032x; 1.0032x over previous
//
#include <hip/hip_runtime.h>
#include <hip/hip_bf16.h>

// Problem: S=2048, D_MODEL=2048, H=16, HD=128
// out = softmax1((q@Wq^T)(k@Wk^T)^T / sqrt(HD)) @ (v@Wv^T) * scalars @ Wo^T
//
// Round 7:
//  - gemm_nt3: XOR bank-swizzle on the LDS k-slot. Previous layout had a
//    4-way ds_read_b128 bank conflict (SQ_LDS_BANK_CONFLICT = 2^23/dispatch,
//    +4 cy/read -> LDS pipe binding at ~2450 cy/K-step vs MFMA 1860).
//    Per guide rule 21 (global_load_lds writes linearly): LDS stays linear,
//    the global SOURCE k-chunk is pre-swizzled (chunk = s ^ (row&3)) and the
//    fragment read uses slot = quad ^ (qr&3). Post-fix pattern is 2-way (free).
//  - attn_mfma: unchanged (142 us; next target after GEMMs).

#define S_LEN 2048
#define DMODEL 2048
#define NHEAD 16
#define HEADD 128

typedef __bf16 bf16x8 __attribute__((ext_vector_type(8)));
typedef __bf16 bf16x4 __attribute__((ext_vector_type(4)));
typedef float f32x4 __attribute__((ext_vector_type(4)));

__device__ inline void async_copy16(const __bf16* g, __bf16* l) {
    __builtin_amdgcn_global_load_lds(
        (const __attribute__((address_space(1))) unsigned int*)g,
        (__attribute__((address_space(3))) unsigned int*)l, 16, 0, 0);
}

// ---- fp32 -> hi/lo bf16 split conversion, up to 2 matrices per launch ----
__global__ __launch_bounds__(256) void conv2(const float* __restrict__ s0,
                                             __hip_bfloat16* __restrict__ h0,
                                             __hip_bfloat16* __restrict__ l0,
                                             float sc0,
                                             const float* __restrict__ s1,
                                             __hip_bfloat16* __restrict__ h1,
                                             __hip_bfloat16* __restrict__ l1,
                                             float sc1) {
    const float* s = blockIdx.y ? s1 : s0;
    __hip_bfloat16* ph = blockIdx.y ? h1 : h0;
    __hip_bfloat16* pl = blockIdx.y ? l1 : l0;
    const float sc = blockIdx.y ? sc1 : sc0;
    size_t i4 = (size_t)blockIdx.x * 256 + threadIdx.x;  // float4 index
    float4 v = *(const float4*)&s[i4 * 4];
    float x0 = v.x * sc, x1 = v.y * sc, x2 = v.z * sc, x3 = v.w * sc;
    bf16x4 hv, lv;
    __bf16 a0 = (__bf16)x0, a1 = (__bf16)x1, a2 = (__bf16)x2, a3 = (__bf16)x3;
    hv[0] = a0; hv[1] = a1; hv[2] = a2; hv[3] = a3;
    lv[0] = (__bf16)(x0 - (float)a0); lv[1] = (__bf16)(x1 - (float)a1);
    lv[2] = (__bf16)(x2 - (float)a2); lv[3] = (__bf16)(x3 - (float)a3);
    *(bf16x4*)&ph[i4 * 4] = hv;
    *(bf16x4*)&pl[i4 * 4] = lv;
}

struct GArgs {
    const __bf16 *Ah, *Al, *Bh, *Bl;
    float* Cf;
    __bf16 *Ch, *Cl;
};

// ---- C = A @ B^T, pre-split hi/lo planes. Tile 128(M) x 64(N), BK=32.
// 128 threads = 2 waves; wave w owns rows [w*64, w*64+64) x all 64 cols.
// LDS k-slot swizzle: LDS row r, 16B-slot s holds global k-chunk (s ^ (r&3)).
// Staging pre-swizzles the GLOBAL address (LDS dest stays linear per
// global_load_lds constraint); fragment reads use slot = quad ^ (qr&3).
// OUTMODE: 0 = fp32, 1 = bf16, 2 = hi/lo bf16 planes. blockIdx.z picks g0/g1.
template <int OUTMODE>
__global__ __launch_bounds__(128, 3) void gemm_nt3(GArgs g0, GArgs g1) {
    constexpr int K = DMODEL, N = DMODEL;
    const GArgs g = blockIdx.z ? g1 : g0;
    __shared__ __bf16 sAh[128 * 32], sAl[128 * 32];
    __shared__ __bf16 sBh[64 * 32], sBl[64 * 32];

    const int tid = threadIdx.x;   // 0..127
    const int lane = tid & 63;
    const int wave = tid >> 6;     // 0..1
    const int qr = lane & 15;
    const int quad = lane >> 4;
    const size_t row0 = (size_t)blockIdx.y * 128;
    const size_t col0 = (size_t)blockIdx.x * 64;

    // staging: chunk (c*128+tid) -> LDS row = c*32 + (tid>>2), slot = tid&3;
    // that slot must hold global k-chunk (slot ^ (row&3)), row&3 = (tid>>2)&3.
    const int srow = tid >> 2;
    const int k8 = (((tid & 3) ^ ((tid >> 2) & 3)) * 8);
    const __bf16* gAh = g.Ah + (row0 + srow) * K + k8;
    const __bf16* gAl = g.Al + (row0 + srow) * K + k8;
    const __bf16* gBh = g.Bh + (col0 + srow) * K + k8;
    const __bf16* gBl = g.Bl + (col0 + srow) * K + k8;

    f32x4 acc[4][4] = {};

    for (int k0 = 0; k0 < K; k0 += 32) {
#pragma unroll
        for (int c = 0; c < 4; ++c) {
            async_copy16(gAh + (size_t)c * 32 * K, sAh + c * 1024 + tid * 8);
            async_copy16(gAl + (size_t)c * 32 * K, sAl + c * 1024 + tid * 8);
        }
#pragma unroll
        for (int c = 0; c < 2; ++c) {
            async_copy16(gBh + (size_t)c * 32 * K, sBh + c * 1024 + tid * 8);
            async_copy16(gBl + (size_t)c * 32 * K, sBl + c * 1024 + tid * 8);
        }
        gAh += 32; gAl += 32; gBh += 32; gBl += 32;
        __syncthreads();

        // read slot = quad ^ (qr&3): undoes the staging swizzle (row&3 = qr&3)
        // and makes consecutive-lane bank-groups 2-way instead of 4-way (free).
        const int aslot = (quad ^ (qr & 3)) * 8;
        bf16x8 a_h[4], a_l[4], b_h[4], b_l[4];
#pragma unroll
        for (int i = 0; i < 4; ++i) {
            a_h[i] = *(const bf16x8*)&sAh[(wave * 64 + i * 16 + qr) * 32 + aslot];
            a_l[i] = *(const bf16x8*)&sAl[(wave * 64 + i * 16 + qr) * 32 + aslot];
        }
#pragma unroll
        for (int j = 0; j < 4; ++j) {
            b_h[j] = *(const bf16x8*)&sBh[(j * 16 + qr) * 32 + aslot];
            b_l[j] = *(const bf16x8*)&sBl[(j * 16 + qr) * 32 + aslot];
        }
#pragma unroll
        for (int i = 0; i < 4; ++i)
#pragma unroll
            for (int j = 0; j < 4; ++j) {
                acc[i][j] = __builtin_amdgcn_mfma_f32_16x16x32_bf16(a_h[i], b_h[j], acc[i][j], 0, 0, 0);
                acc[i][j] = __builtin_amdgcn_mfma_f32_16x16x32_bf16(a_h[i], b_l[j], acc[i][j], 0, 0, 0);
                acc[i][j] = __builtin_amdgcn_mfma_f32_16x16x32_bf16(a_l[i], b_h[j], acc[i][j], 0, 0, 0);
            }
        __syncthreads();
    }

    // epilogue: C/D layout col=lane&15, row=quad*4+reg
#pragma unroll
    for (int i = 0; i < 4; ++i)
#pragma unroll
        for (int j = 0; j < 4; ++j)
#pragma unroll
            for (int r = 0; r < 4; ++r) {
                size_t idx = (row0 + wave * 64 + i * 16 + quad * 4 + r) * N +
                             col0 + j * 16 + qr;
                float x = acc[i][j][r];
                if (OUTMODE == 0) {
                    g.Cf[idx] = x;
                } else if (OUTMODE == 1) {
                    g.Ch[idx] = (__bf16)x;
                } else {
                    __bf16 hv = (__bf16)x;
                    g.Ch[idx] = hv;
                    g.Cl[idx] = (__bf16)(x - (float)hv);
                }
            }
}

// MFMA flash attention. Block = 64 q-rows x 1 head; 4 waves x 16 rows each.
__global__ __launch_bounds__(256) void attn_mfma(const __bf16* __restrict__ qhi_g,
                                                 const __bf16* __restrict__ qlo_g,
                                                 const __bf16* __restrict__ khi_g,
                                                 const __bf16* __restrict__ klo_g,
                                                 const __bf16* __restrict__ vhT,
                                                 const float* __restrict__ scalars,
                                                 __bf16* __restrict__ ohi_g,
                                                 __bf16* __restrict__ olo_g) {
    const int h = blockIdx.y;
    const int q0 = blockIdx.x * 64;
    __shared__ __align__(16) __bf16 Khi[64][136];  // padded: 272B stride
    __shared__ __align__(16) __bf16 Klo[64][136];
    __shared__ __align__(16) __bf16 VT[128][72];   // [head-dim][kpos], 144B stride
    __shared__ __align__(16) __bf16 Ps[64][72];    // [q-row][kpos]

    const int tid = threadIdx.x;
    const int lane = tid & 63;
    const int wave = tid >> 6;
    const int qr = lane & 15;
    const int quad = lane >> 4;

    bf16x8 qfh[4], qfl[4];
    {
        const __bf16* qrh = qhi_g + (size_t)(q0 + wave * 16 + qr) * DMODEL + h * HEADD;
        const __bf16* qrl = qlo_g + (size_t)(q0 + wave * 16 + qr) * DMODEL + h * HEADD;
#pragma unroll
        for (int kc = 0; kc < 4; ++kc) {
            qfh[kc] = *(const bf16x8*)&qrh[kc * 32 + quad * 8];
            qfl[kc] = *(const bf16x8*)&qrl[kc * 32 + quad * 8];
        }
    }

    f32x4 oacc[8] = {};
    float m_r[4], l_r[4];
#pragma unroll
    for (int r = 0; r < 4; ++r) { m_r[r] = 0.f; l_r[r] = 1.f; }  // softmax1 init

    for (int k0 = 0; k0 < S_LEN; k0 += 64) {
#pragma unroll
        for (int i = 0; i < 4; ++i) {
            int idx = tid + i * 256;
            int kp = idx >> 4;
            int c8 = (idx & 15) * 8;
            size_t goff = (size_t)(k0 + kp) * DMODEL + h * HEADD + c8;
            *(bf16x8*)&Khi[kp][c8] = *(const bf16x8*)&khi_g[goff];
            *(bf16x8*)&Klo[kp][c8] = *(const bf16x8*)&klo_g[goff];
        }
#pragma unroll
        for (int i = 0; i < 4; ++i) {
            int idx = tid + i * 256;
            int dm = idx >> 3;
            int c8 = (idx & 7) * 8;
            *(bf16x8*)&VT[dm][c8] =
                *(const bf16x8*)&vhT[(size_t)(h * HEADD + dm) * S_LEN + k0 + c8];
        }
        __syncthreads();

        f32x4 S[4] = {};
#pragma unroll
        for (int jt = 0; jt < 4; ++jt) {
#pragma unroll
            for (int kc = 0; kc < 4; ++kc) {
                bf16x8 kh8 = *(const bf16x8*)&Khi[jt * 16 + qr][kc * 32 + quad * 8];
                bf16x8 kl8 = *(const bf16x8*)&Klo[jt * 16 + qr][kc * 32 + quad * 8];
                S[jt] = __builtin_amdgcn_mfma_f32_16x16x32_bf16(qfh[kc], kh8, S[jt], 0, 0, 0);
                S[jt] = __builtin_amdgcn_mfma_f32_16x16x32_bf16(qfh[kc], kl8, S[jt], 0, 0, 0);
                S[jt] = __builtin_amdgcn_mfma_f32_16x16x32_bf16(qfl[kc], kh8, S[jt], 0, 0, 0);
            }
        }

#pragma unroll
        for (int r = 0; r < 4; ++r) {
            float mx = fmaxf(fmaxf(S[0][r], S[1][r]), fmaxf(S[2][r], S[3][r]));
#pragma unroll
            for (int m = 1; m < 16; m <<= 1) mx = fmaxf(mx, __shfl_xor(mx, m, 64));
            float m_new = fmaxf(m_r[r], mx);
            float alpha = __expf(m_r[r] - m_new);
            float sum = 0.f;
            int prow = wave * 16 + quad * 4 + r;
#pragma unroll
            for (int jt = 0; jt < 4; ++jt) {
                float e = __expf(S[jt][r] - m_new);
                sum += e;
                Ps[prow][jt * 16 + qr] = (__bf16)e;
            }
#pragma unroll
            for (int m = 1; m < 16; m <<= 1) sum += __shfl_xor(sum, m, 64);
            l_r[r] = l_r[r] * alpha + sum;
            m_r[r] = m_new;
#pragma unroll
            for (int nt = 0; nt < 8; ++nt) oacc[nt][r] *= alpha;
        }
        __syncthreads();

#pragma unroll
        for (int kc = 0; kc < 2; ++kc) {
            bf16x8 pf = *(const bf16x8*)&Ps[wave * 16 + qr][kc * 32 + quad * 8];
#pragma unroll
            for (int nt = 0; nt < 8; ++nt) {
                bf16x8 vf = *(const bf16x8*)&VT[nt * 16 + qr][kc * 32 + quad * 8];
                oacc[nt] = __builtin_amdgcn_mfma_f32_16x16x32_bf16(pf, vf, oacc[nt], 0, 0, 0);
            }
        }
        __syncthreads();
    }

    const float sh = scalars[h];
#pragma unroll
    for (int r = 0; r < 4; ++r) {
        float wm = sh / l_r[r];
        size_t rowoff = (size_t)(q0 + wave * 16 + quad * 4 + r) * DMODEL + h * HEADD;
#pragma unroll
        for (int nt = 0; nt < 8; ++nt) {
            float x = oacc[nt][r] * wm;
            __bf16 hv = (__bf16)x;
            ohi_g[rowoff + nt * 16 + qr] = hv;
            olo_g[rowoff + nt * 16 + qr] = (__bf16)(x - (float)hv);
        }
    }
}

extern "C" void kernel_launch(void* const* d_in, const int* in_sizes, int n_in,
                              void* d_out, int out_size, void* d_ws, size_t ws_size,
                              hipStream_t stream) {
    const float* query   = (const float*)d_in[0];
    const float* key_    = (const float*)d_in[1];
    const float* value   = (const float*)d_in[2];
    const float* Wq      = (const float*)d_in[3];
    const float* Wk      = (const float*)d_in[4];
    const float* Wv      = (const float*)d_in[5];
    const float* Wo      = (const float*)d_in[6];
    const float* scalars = (const float*)d_in[7];
    float* out = (float*)d_out;

    const size_t PL = (size_t)S_LEN * DMODEL;  // elements per 8 MB plane
    __bf16* p[12];
    for (int i = 0; i < 12; ++i) p[i] = (__bf16*)d_ws + i * PL;  // 96 MB total
    // p0..p3: input slot A (act hi/lo, wt hi/lo) — reused
    // p4..p7: input slot B (also later: p4 = vhT)
    // p8,p9: qh hi/lo (later attn-out hi/lo); p10,p11: kh hi/lo

    const float scale = 0.08838834764831844f;  // 1/sqrt(128)
    dim3 cg(2048 * 2048 / 4 / 256, 2), cb(256);
    dim3 gg(DMODEL / 64, S_LEN / 128, 1), gb(128);
    dim3 gg2(DMODEL / 64, S_LEN / 128, 2);

#define BH(x) (__hip_bfloat16*)(x)
    conv2<<<cg, cb, 0, stream>>>(query, BH(p[0]), BH(p[1]), 1.0f,
                                 Wq, BH(p[2]), BH(p[3]), scale);
    conv2<<<cg, cb, 0, stream>>>(key_, BH(p[4]), BH(p[5]), 1.0f,
                                 Wk, BH(p[6]), BH(p[7]), 1.0f);
    {
        GArgs gq = {p[0], p[1], p[2], p[3], nullptr, p[8], p[9]};
        GArgs gk = {p[4], p[5], p[6], p[7], nullptr, p[10], p[11]};
        gemm_nt3<2><<<gg2, gb, 0, stream>>>(gq, gk);
    }
    conv2<<<cg, cb, 0, stream>>>(Wv, BH(p[0]), BH(p[1]), 1.0f,
                                 value, BH(p[2]), BH(p[3]), 1.0f);
    {
        // vhT = (value @ Wv^T)^T = Wv @ value^T  (A = Wv, B = value)
        GArgs gv = {p[0], p[1], p[2], p[3], nullptr, p[4], nullptr};
        gemm_nt3<1><<<gg, gb, 0, stream>>>(gv, gv);
    }

    attn_mfma<<<dim3(S_LEN / 64, NHEAD), 256, 0, stream>>>(
        p[8], p[9], p[10], p[11], p[4], scalars, p[8], p[9]);

    conv2<<<dim3(2048 * 2048 / 4 / 256, 1), cb, 0, stream>>>(
        Wo, BH(p[0]), BH(p[1]), 1.0f, Wo, BH(p[0]), BH(p[1]), 1.0f);
    {
        GArgs go = {p[8], p[9], p[0], p[1], out, nullptr, nullptr};
        gemm_nt3<0><<<gg, gb, 0, stream>>>(go, go);
    }
#undef BH
}